// Round 5
// baseline (414.399 us; speedup 1.0000x reference)
//
#include <hip/hip_runtime.h>

typedef float f32x4 __attribute__((ext_vector_type(4)));
typedef short bf16x8 __attribute__((ext_vector_type(8)));

#define NTOK 8192
#define DIM  1024
#define NE   8
#define NH   512
#define NO   1024

static __device__ __forceinline__ unsigned short f2bf(float f) {
  unsigned u = __float_as_uint(f);
  u += 0x7fffu + ((u >> 16) & 1u);
  return (unsigned short)(u >> 16);
}
static __device__ __forceinline__ unsigned pk2(float a, float b) {
  return (unsigned)f2bf(a) | ((unsigned)f2bf(b) << 16);
}

static __device__ __forceinline__ f32x4 mfma_bf16(bf16x8 a, bf16x8 b, f32x4 c) {
  return __builtin_amdgcn_mfma_f32_16x16x32_bf16(a, b, c, 0, 0, 0);
}

// ---------------------------------------------------------------------------
// Gate: fp64 logits (match np ranking), top-4 -> one bitmask byte per token
// ---------------------------------------------------------------------------
__global__ __launch_bounds__(256) void gate_kernel(
    const float* __restrict__ x, const float* __restrict__ wg,
    unsigned char* __restrict__ msk8)
{
  const int lane = threadIdx.x & 63;
  const int wv = threadIdx.x >> 6;
  const int n = blockIdx.x * 4 + wv;
  const float* xr = x + (size_t)n * DIM;
  float4 v[4];
#pragma unroll
  for (int i = 0; i < 4; ++i) v[i] = *(const float4*)(xr + i * 256 + lane * 4);
  double logit[NE];
#pragma unroll
  for (int e = 0; e < NE; ++e) {
    const float* wr = wg + e * DIM;
    double s = 0.0;
#pragma unroll
    for (int i = 0; i < 4; ++i) {
      float4 g = *(const float4*)(wr + i * 256 + lane * 4);
      s += (double)v[i].x * g.x + (double)v[i].y * g.y +
           (double)v[i].z * g.z + (double)v[i].w * g.w;
    }
#pragma unroll
    for (int off = 32; off; off >>= 1) s += __shfl_down(s, off);
    logit[e] = s;
  }
  if (lane == 0) {
    unsigned sel = 0;
#pragma unroll
    for (int t = 0; t < 4; ++t) {
      int best = 0; double bv = -1.0e300;
#pragma unroll
      for (int e = 0; e < NE; ++e)
        if (!((sel >> e) & 1) && logit[e] > bv) { bv = logit[e]; best = e; }
      sel |= 1u << best;
    }
    msk8[n] = (unsigned char)sel;
  }
}

// ---------------------------------------------------------------------------
// Weight packs (unchanged): fragment-major bf16.
// w1p [e][nt:32][ks:32][lane:64][j:8]; elem = w1[e][nt*16+(l&15)][ks*32+(l>>4)*8+j]
// w2p [e][ot:64][ks2:16][lane:64][j:8]; elem = w2[e][ot*16+(l&15)][ks2*32+(l>>4)*8+j]
// ---------------------------------------------------------------------------
__global__ __launch_bounds__(256) void pack_w1_kernel(
    const float* __restrict__ w1, unsigned short* __restrict__ w1p)
{
  int t = blockIdx.x * 256 + threadIdx.x;
  int lane = t & 63, ks = (t >> 6) & 31, nt = (t >> 11) & 31, e = t >> 16;
  int r = nt * 16 + (lane & 15);
  int c = ks * 32 + (lane >> 4) * 8;
  const float* src = w1 + ((size_t)(e * 512 + r)) * 1024 + c;
  float4 f0 = *(const float4*)src;
  float4 f1 = *(const float4*)(src + 4);
  uint4 v;
  v.x = pk2(f0.x, f0.y); v.y = pk2(f0.z, f0.w);
  v.z = pk2(f1.x, f1.y); v.w = pk2(f1.z, f1.w);
  *(uint4*)(w1p + (size_t)t * 8) = v;
}

__global__ __launch_bounds__(256) void pack_w2_kernel(
    const float* __restrict__ w2, unsigned short* __restrict__ w2p)
{
  int t = blockIdx.x * 256 + threadIdx.x;
  int lane = t & 63, ks = (t >> 6) & 15, ot = (t >> 10) & 63, e = t >> 16;
  int o = ot * 16 + (lane & 15);
  int h = ks * 32 + (lane >> 4) * 8;
  const float* src = w2 + ((size_t)(e * 1024 + o)) * 512 + h;
  float4 f0 = *(const float4*)src;
  float4 f1 = *(const float4*)(src + 4);
  uint4 v;
  v.x = pk2(f0.x, f0.y); v.y = pk2(f0.z, f0.w);
  v.z = pk2(f1.x, f1.y); v.w = pk2(f1.z, f1.w);
  *(uint4*)(w2p + (size_t)t * 8) = v;
}

// ---------------------------------------------------------------------------
// Fused MoE FFN, round 5: BM=64 tokens, out-column split (z half), 16 waves.
// Same 2-barrier-per-phase template as round 3 (replay-safe), new geometry:
//   block (t,z): tokens t*64..+64, out cols z*512..+512
//   per expert e, per H-half hh: GEMM1(1m x 4n/wave) -> hs -> GEMM2(1m x 8n)
//   xs 128 KB + hs 32 KB = 160 KB LDS; mask = 1 dword of bits per thread
// ---------------------------------------------------------------------------
__global__ __launch_bounds__(1024, 4) void moe_ffn(
    const float* __restrict__ x, const unsigned short* __restrict__ w1p,
    const unsigned short* __restrict__ w2p, const unsigned char* __restrict__ msk8,
    float* __restrict__ out)
{
  __shared__ unsigned short xs[128 * 64 * 8];  // 128 KB: 128 frags (ks*4+m)
  __shared__ unsigned short hs[32 * 64 * 8];   // 32 KB: 32 frags (ks2*4+m)

  const int tid = threadIdx.x;
  const int lane = tid & 63;
  const int wv = tid >> 6;
  const int rw4 = wv & 3;        // row-frag owned by this wave (m index)
  const int cw4 = wv >> 2;       // col group
  const int row0 = (blockIdx.x >> 1) * 64;
  const int z = blockIdx.x & 1;
  const int arow = lane & 15;
  const int kch = lane >> 4;

  // ---- stage X: 64 rows x 1024 f32 -> bf16 fragment-major ---------------
#pragma unroll
  for (int i = 0; i < 8; ++i) {
    int c = i * 1024 + tid;          // 0..8191 = 64 rows x 128 chunks
    int r = c >> 7;
    int ch = c & 127;
    const float* src = x + (size_t)(row0 + r) * DIM + ch * 8;
    float4 f0 = *(const float4*)src;
    float4 f1 = *(const float4*)(src + 4);
    uint4 v;
    v.x = pk2(f0.x, f0.y); v.y = pk2(f0.z, f0.w);
    v.z = pk2(f1.x, f1.y); v.w = pk2(f1.z, f1.w);
    int f = (ch >> 2) * 4 + (r >> 4);            // ks*4 + m
    int l = ((ch & 3) << 4) | (r & 15);          // kch<<4 | row
    *(uint4*)(xs + ((size_t)(f * 64 + l)) * 8) = v;
  }
  // per-thread top-k bits for my 4 rows (row0 + rw4*16 + kch*4 + j), j=byte
  const unsigned mbits = *(const unsigned*)(msk8 + row0 + rw4 * 16 + kch * 4);
  __syncthreads();

  const unsigned short* xp = xs + lane * 8;
  const unsigned short* hp = hs + lane * 8;

  f32x4 oacc[8];
#pragma unroll
  for (int n = 0; n < 8; ++n) oacc[n] = f32x4{0.f, 0.f, 0.f, 0.f};

  for (int e = 0; e < NE; ++e) {
#pragma unroll
    for (int hh = 0; hh < 2; ++hh) {
      // ---- GEMM1-half: h[64 x 256] slice, wave = 1m x 4n ----------------
      f32x4 hacc[4];
#pragma unroll
      for (int n = 0; n < 4; ++n) hacc[n] = f32x4{0.f, 0.f, 0.f, 0.f};

      const unsigned short* pb =
          w1p + ((size_t)(e * 32 + hh * 16 + cw4 * 4) * 32) * 512 + lane * 8;
#pragma unroll 2
      for (int ks = 0; ks < 32; ++ks) {
        bf16x8 a = *(const bf16x8*)(xp + (ks * 4 + rw4) * 512);
#pragma unroll
        for (int n = 0; n < 4; ++n) {
          bf16x8 b = *(const bf16x8*)(pb + (size_t)n * 16384 + ks * 512);
          hacc[n] = mfma_bf16(a, b, hacc[n]);
        }
      }
      __syncthreads();   // all waves done reading hs (previous phase GEMM2)

      // ---- epilogue: relu * mask-bit -> hs fragments --------------------
#pragma unroll
      for (int n = 0; n < 4; ++n)
#pragma unroll
        for (int j = 0; j < 4; ++j) {
          float v = fmaxf(hacc[n][j], 0.0f);
          v = ((mbits >> (j * 8 + e)) & 1u) ? v : 0.0f;
          int f = (cw4 * 2 + (n >> 1)) * 4 + rw4;
          int l2 = (((n & 1) * 2 + (arow >> 3)) << 4) | (kch * 4 + j);
          hs[((size_t)(f * 64 + l2)) * 8 + (arow & 7)] = f2bf(v);
        }
      __syncthreads();   // hs ready

      // ---- GEMM2-half: out[64 x 512-slice] += hs @ W2[e]^T, wave = 1m x 8n
      const unsigned short* pc =
          w2p + ((size_t)((e * 64 + z * 32 + cw4 * 8) * 16 + hh * 8)) * 512 + lane * 8;
#pragma unroll 2
      for (int ks2 = 0; ks2 < 8; ++ks2) {
        bf16x8 a = *(const bf16x8*)(hp + (ks2 * 4 + rw4) * 512);
#pragma unroll
        for (int n = 0; n < 8; ++n) {
          bf16x8 b = *(const bf16x8*)(pc + (size_t)n * 8192 + ks2 * 512);
          oacc[n] = mfma_bf16(a, b, oacc[n]);
        }
      }
    }
  }

  // ---- write out (each element exactly once across grid) -----------------
#pragma unroll
  for (int n = 0; n < 8; ++n)
#pragma unroll
    for (int j = 0; j < 4; ++j) {
      int row = row0 + rw4 * 16 + kch * 4 + j;
      int col = z * 512 + (cw4 * 8 + n) * 16 + arow;
      out[(size_t)row * NO + col] = oacc[n][j];
    }
}

extern "C" void kernel_launch(void* const* d_in, const int* in_sizes, int n_in,
                              void* d_out, int out_size, void* d_ws, size_t ws_size,
                              hipStream_t stream) {
  (void)in_sizes; (void)n_in; (void)out_size; (void)ws_size;
  const float* x  = (const float*)d_in[0];
  const float* wg = (const float*)d_in[1];
  const float* w1 = (const float*)d_in[2];
  const float* w2 = (const float*)d_in[3];
  float* out = (float*)d_out;
  char* ws = (char*)d_ws;
  unsigned short* w1p = (unsigned short*)ws;                        // 8 MB
  unsigned short* w2p = (unsigned short*)(ws + ((size_t)8 << 20));  // 8 MB
  unsigned char* msk8 = (unsigned char*)(ws + ((size_t)16 << 20));  // 8 KB

  gate_kernel<<<2048, 256, 0, stream>>>(x, wg, msk8);
  pack_w1_kernel<<<2048, 256, 0, stream>>>(w1, w1p);
  pack_w2_kernel<<<2048, 256, 0, stream>>>(w2, w2p);
  moe_ffn<<<256, 1024, 0, stream>>>(x, w1p, w2p, msk8, out);
}

// Round 6
// 199.138 us; speedup vs baseline: 2.0810x; 2.0810x over previous
//
#include <hip/hip_runtime.h>

typedef float f32x4 __attribute__((ext_vector_type(4)));
typedef short bf16x8 __attribute__((ext_vector_type(8)));

#define NTOK 8192
#define DIM  1024
#define NE   8
#define NH   512
#define NO   1024

static __device__ __forceinline__ unsigned short f2bf(float f) {
  unsigned u = __float_as_uint(f);
  u += 0x7fffu + ((u >> 16) & 1u);
  return (unsigned short)(u >> 16);
}
static __device__ __forceinline__ unsigned pk2(float a, float b) {
  return (unsigned)f2bf(a) | ((unsigned)f2bf(b) << 16);
}

static __device__ __forceinline__ f32x4 mfma_bf16(bf16x8 a, bf16x8 b, f32x4 c) {
  return __builtin_amdgcn_mfma_f32_16x16x32_bf16(a, b, c, 0, 0, 0);
}

// ---------------------------------------------------------------------------
// Gate: fp64 logits -> top-4 bitmask byte per token.  Also zeroes d_out
// (16 floats per thread) so moe_ffn can atomicAdd partials — stream-ordered,
// same work every call.
// ---------------------------------------------------------------------------
__global__ __launch_bounds__(256) void gate_kernel(
    const float* __restrict__ x, const float* __restrict__ wg,
    unsigned char* __restrict__ msk8, float* __restrict__ out)
{
  // zero my 16-float slice of out (524288 threads x 16 = 8.4M floats)
  {
    size_t t = (size_t)blockIdx.x * 256 + threadIdx.x;
    float4* op = (float4*)(out + t * 16);
    float4 z4 = {0.f, 0.f, 0.f, 0.f};
    op[0] = z4; op[1] = z4; op[2] = z4; op[3] = z4;
  }
  const int lane = threadIdx.x & 63;
  const int wv = threadIdx.x >> 6;
  const int n = blockIdx.x * 4 + wv;
  const float* xr = x + (size_t)n * DIM;
  float4 v[4];
#pragma unroll
  for (int i = 0; i < 4; ++i) v[i] = *(const float4*)(xr + i * 256 + lane * 4);
  double logit[NE];
#pragma unroll
  for (int e = 0; e < NE; ++e) {
    const float* wr = wg + e * DIM;
    double s = 0.0;
#pragma unroll
    for (int i = 0; i < 4; ++i) {
      float4 g = *(const float4*)(wr + i * 256 + lane * 4);
      s += (double)v[i].x * g.x + (double)v[i].y * g.y +
           (double)v[i].z * g.z + (double)v[i].w * g.w;
    }
#pragma unroll
    for (int off = 32; off; off >>= 1) s += __shfl_down(s, off);
    logit[e] = s;
  }
  if (lane == 0) {
    unsigned sel = 0;
#pragma unroll
    for (int t = 0; t < 4; ++t) {
      int best = 0; double bv = -1.0e300;
#pragma unroll
      for (int e = 0; e < NE; ++e)
        if (!((sel >> e) & 1) && logit[e] > bv) { bv = logit[e]; best = e; }
      sel |= 1u << best;
    }
    msk8[n] = (unsigned char)sel;
  }
}

// ---------------------------------------------------------------------------
// Weight packs (unchanged): fragment-major bf16.
// w1p [e][nt:32][ks:32][lane:64][j:8]; elem = w1[e][nt*16+(l&15)][ks*32+(l>>4)*8+j]
// w2p [e][ot:64][ks2:16][lane:64][j:8]; elem = w2[e][ot*16+(l&15)][ks2*32+(l>>4)*8+j]
// ---------------------------------------------------------------------------
__global__ __launch_bounds__(256) void pack_w1_kernel(
    const float* __restrict__ w1, unsigned short* __restrict__ w1p)
{
  int t = blockIdx.x * 256 + threadIdx.x;
  int lane = t & 63, ks = (t >> 6) & 31, nt = (t >> 11) & 31, e = t >> 16;
  int r = nt * 16 + (lane & 15);
  int c = ks * 32 + (lane >> 4) * 8;
  const float* src = w1 + ((size_t)(e * 512 + r)) * 1024 + c;
  float4 f0 = *(const float4*)src;
  float4 f1 = *(const float4*)(src + 4);
  uint4 v;
  v.x = pk2(f0.x, f0.y); v.y = pk2(f0.z, f0.w);
  v.z = pk2(f1.x, f1.y); v.w = pk2(f1.z, f1.w);
  *(uint4*)(w1p + (size_t)t * 8) = v;
}

__global__ __launch_bounds__(256) void pack_w2_kernel(
    const float* __restrict__ w2, unsigned short* __restrict__ w2p)
{
  int t = blockIdx.x * 256 + threadIdx.x;
  int lane = t & 63, ks = (t >> 6) & 15, ot = (t >> 10) & 63, e = t >> 16;
  int o = ot * 16 + (lane & 15);
  int h = ks * 32 + (lane >> 4) * 8;
  const float* src = w2 + ((size_t)(e * 1024 + o)) * 512 + h;
  float4 f0 = *(const float4*)src;
  float4 f1 = *(const float4*)(src + 4);
  uint4 v;
  v.x = pk2(f0.x, f0.y); v.y = pk2(f0.z, f0.w);
  v.z = pk2(f1.x, f1.y); v.w = pk2(f1.z, f1.w);
  *(uint4*)(w2p + (size_t)t * 8) = v;
}

// ---------------------------------------------------------------------------
// Fused MoE FFN, round 6: BM=64 tokens, H-SPLIT (z = hidden half), 16 waves.
// ZERO cross-wave B duplication:
//   GEMM1: wave = 4m x 1n  (16 waves <-> 16 H-frags of the half)
//   GEMM2: wave = 4m x 4n  (16 waves <-> 64 O-frags), partial over H-half
// Per block: 4 MB w1-half + 4 MB w2-half, each byte loaded exactly once.
// Partial outputs combined via atomicAdd (out zeroed by gate_kernel).
// xs 128 KB + hs 32 KB = 160 KB LDS. Same 2-barrier template as round 3.
// ---------------------------------------------------------------------------
__global__ __launch_bounds__(1024, 4) void moe_ffn(
    const float* __restrict__ x, const unsigned short* __restrict__ w1p,
    const unsigned short* __restrict__ w2p, const unsigned char* __restrict__ msk8,
    float* __restrict__ out)
{
  __shared__ unsigned short xs[128 * 64 * 8];  // 128 KB: frag f = ks*4+m
  __shared__ unsigned short hs[32 * 64 * 8];   // 32 KB: frag f = ks2*4+m

  const int tid = threadIdx.x;
  const int lane = tid & 63;
  const int wv = tid >> 6;
  const int row0 = (blockIdx.x >> 1) * 64;
  const int z = blockIdx.x & 1;                // H-half
  const int arow = lane & 15;
  const int kch = lane >> 4;

  // ---- stage X: 64 rows x 1024 f32 -> bf16 fragment-major ---------------
#pragma unroll
  for (int i = 0; i < 8; ++i) {
    int c = i * 1024 + tid;          // 64 rows x 128 chunks-of-8
    int r = c >> 7;
    int ch = c & 127;
    const float* src = x + (size_t)(row0 + r) * DIM + ch * 8;
    float4 f0 = *(const float4*)src;
    float4 f1 = *(const float4*)(src + 4);
    uint4 v;
    v.x = pk2(f0.x, f0.y); v.y = pk2(f0.z, f0.w);
    v.z = pk2(f1.x, f1.y); v.w = pk2(f1.z, f1.w);
    int f = (ch >> 2) * 4 + (r >> 4);            // ks*4 + m
    int l = ((ch & 3) << 4) | (r & 15);          // kch<<4 | row
    *(uint4*)(xs + ((size_t)(f * 64 + l)) * 8) = v;
  }
  __syncthreads();

  const unsigned short* xp = xs + lane * 8;
  const unsigned short* hp = hs + lane * 8;

  f32x4 oacc[4][4];
#pragma unroll
  for (int m = 0; m < 4; ++m)
#pragma unroll
    for (int n = 0; n < 4; ++n) oacc[m][n] = f32x4{0.f, 0.f, 0.f, 0.f};

  for (int e = 0; e < NE; ++e) {
    // ---- GEMM1: wave owns H-frag (z*16+wv); 4m x 1n; B unique per wave --
    f32x4 hacc[4];
#pragma unroll
    for (int m = 0; m < 4; ++m) hacc[m] = f32x4{0.f, 0.f, 0.f, 0.f};

    const unsigned short* pb =
        w1p + ((size_t)(e * 32 + z * 16 + wv) * 32) * 512 + lane * 8;
#pragma unroll 4
    for (int ks = 0; ks < 32; ++ks) {
      bf16x8 b = *(const bf16x8*)(pb + ks * 512);
#pragma unroll
      for (int m = 0; m < 4; ++m) {
        bf16x8 a = *(const bf16x8*)(xp + (ks * 4 + m) * 512);
        hacc[m] = mfma_bf16(a, b, hacc[m]);
      }
    }
    __syncthreads();   // all waves done reading hs (previous expert GEMM2)

    // ---- epilogue: relu * mask-bit -> hs fragments ----------------------
    // value (r = m*16+kch*4+j, c = wv*16+arow within half):
    //   f = (wv>>1)*4 + m; l2 = ((wv&1)*2 + (arow>>3))<<4 | (kch*4+j); j2 = arow&7
#pragma unroll
    for (int m = 0; m < 4; ++m) {
      const unsigned mb = *(const unsigned*)(msk8 + row0 + m * 16 + kch * 4);
#pragma unroll
      for (int j = 0; j < 4; ++j) {
        float v = fmaxf(hacc[m][j], 0.0f);
        v = ((mb >> (j * 8 + e)) & 1u) ? v : 0.0f;
        int f = (wv >> 1) * 4 + m;
        int l2 = (((wv & 1) * 2 + (arow >> 3)) << 4) | (kch * 4 + j);
        hs[((size_t)(f * 64 + l2)) * 8 + (arow & 7)] = f2bf(v);
      }
    }
    __syncthreads();   // hs ready

    // ---- GEMM2: out[64 x 1024] += hs_half @ W2[e][:, half]; 4m x 4n -----
    const unsigned short* pc =
        w2p + ((size_t)((e * 64 + wv * 4) * 16 + z * 8)) * 512 + lane * 8;
#pragma unroll 2
    for (int ks2 = 0; ks2 < 8; ++ks2) {
      bf16x8 a0 = *(const bf16x8*)(hp + (ks2 * 4 + 0) * 512);
      bf16x8 a1 = *(const bf16x8*)(hp + (ks2 * 4 + 1) * 512);
      bf16x8 a2 = *(const bf16x8*)(hp + (ks2 * 4 + 2) * 512);
      bf16x8 a3 = *(const bf16x8*)(hp + (ks2 * 4 + 3) * 512);
#pragma unroll
      for (int n = 0; n < 4; ++n) {
        bf16x8 b = *(const bf16x8*)(pc + (size_t)n * 8192 + ks2 * 512);
        oacc[0][n] = mfma_bf16(a0, b, oacc[0][n]);
        oacc[1][n] = mfma_bf16(a1, b, oacc[1][n]);
        oacc[2][n] = mfma_bf16(a2, b, oacc[2][n]);
        oacc[3][n] = mfma_bf16(a3, b, oacc[3][n]);
      }
    }
  }

  // ---- atomic partial-sum into out ---------------------------------------
#pragma unroll
  for (int m = 0; m < 4; ++m)
#pragma unroll
    for (int n = 0; n < 4; ++n)
#pragma unroll
      for (int j = 0; j < 4; ++j) {
        int row = row0 + m * 16 + kch * 4 + j;
        int col = (wv * 4 + n) * 16 + arow;
        atomicAdd(&out[(size_t)row * NO + col], oacc[m][n][j]);
      }
}

extern "C" void kernel_launch(void* const* d_in, const int* in_sizes, int n_in,
                              void* d_out, int out_size, void* d_ws, size_t ws_size,
                              hipStream_t stream) {
  (void)in_sizes; (void)n_in; (void)out_size; (void)ws_size;
  const float* x  = (const float*)d_in[0];
  const float* wg = (const float*)d_in[1];
  const float* w1 = (const float*)d_in[2];
  const float* w2 = (const float*)d_in[3];
  float* out = (float*)d_out;
  char* ws = (char*)d_ws;
  unsigned short* w1p = (unsigned short*)ws;                        // 8 MB
  unsigned short* w2p = (unsigned short*)(ws + ((size_t)8 << 20));  // 8 MB
  unsigned char* msk8 = (unsigned char*)(ws + ((size_t)16 << 20));  // 8 KB

  gate_kernel<<<2048, 256, 0, stream>>>(x, wg, msk8, out);
  pack_w1_kernel<<<2048, 256, 0, stream>>>(w1, w1p);
  pack_w2_kernel<<<2048, 256, 0, stream>>>(w2, w2p);
  moe_ffn<<<256, 1024, 0, stream>>>(x, w1p, w2p, msk8, out);
}